// Round 9
// baseline (126.511 us; speedup 1.0000x reference)
//
#include <hip/hip_runtime.h>

#define THREADS 256

// problem sizes
#define Bsz 2
#define HWp 16384          // 128*128
#define Ntot (Bsz*HWp)     // 32768
#define HID 256
#define Mm 1728
#define FMC 17
#define W_OFF 98304        // 'out' elements precede 'weights' in d_out

// ws layout (in floats)
#define F1_OFF  0
#define F1_SZ   (Bsz*16*HWp)                 // 524288
#define FM_OFF  F1_SZ                        // 32768*17
#define WB2_OFF (FM_OFF + Ntot*FMC)          // bf16 B2 frags: 442368 shorts
#define WB1_OFF (WB2_OFF + (Mm*HID)/2)       // bf16 w1 frags: 8192 shorts

typedef __attribute__((ext_vector_type(8))) short bf16x8;
typedef __attribute__((ext_vector_type(4))) float f32x4;

static __device__ __forceinline__ short f2bf(float x) {
    unsigned u = __builtin_bit_cast(unsigned, x);
    unsigned r = (u + 0x7fff + ((u >> 16) & 1)) >> 16;
    return (short)r;
}

// ---------- K13: conv1 (blocks<256) + wB2 cvt (256..1983) + wB1 pack (1984) --
__global__ __launch_bounds__(THREADS) void k13_conv1_cvt(const float* __restrict__ feat,
                                                         const float* __restrict__ w1,
                                                         const float* __restrict__ b1,
                                                         float* __restrict__ f1,
                                                         const float* __restrict__ w2g,
                                                         short* __restrict__ wB2,
                                                         const float* __restrict__ w1g,
                                                         short* __restrict__ wB1) {
    int tid = threadIdx.x;
    if (blockIdx.x >= 1984) {
        // pack w1 (256x17 f32) -> MFMA B-frags bf16, K padded to 32
        for (int idx = tid; idx < 8192; idx += THREADS) {
            int i = idx & 7, l = (idx >> 3) & 63, h = idx >> 9;
            int k = (l >> 4) * 8 + i, hid = h * 16 + (l & 15);
            wB1[idx] = (k < FMC) ? f2bf(w1g[hid * FMC + k]) : (short)0;
        }
        return;
    }
    if (blockIdx.x >= 256) {
        // f2w2_w (1728x256 fp32) -> bf16 fragment-major
        int t = (blockIdx.x - 256) * THREADS + tid;
        int i = t & 7, l = (t >> 3) & 63, ct = (t >> 9) & 3, s = (t >> 11) & 7, mc = t >> 14;
        int col = mc * 64 + ct * 16 + (l & 15);
        int k = s * 32 + (l >> 4) * 8 + i;
        wB2[t] = f2bf(w2g[col * HID + k]);
        return;
    }
    __shared__ float sW[4 * 64 * 4];   // [pp][ic][u*2+v] for this block's oc
    int b = blockIdx.x;
    int rb = b & 7, oc = (b >> 3) & 15, bb = b >> 7;
    int c = tid & 63, sr = tid >> 6;
    int r0 = rb * 4 + sr;              // 0..31
    int r1 = r0 + 32;                  // 32..63

    #pragma unroll
    for (int q = 0; q < 4; ++q) {
        int e = tid * 4 + q;
        int v = e & 1, u = (e >> 1) & 1, ic = (e >> 2) & 63, pp = (e >> 8) & 3;
        int pi = pp >> 1, pj = pp & 1;
        float s = 0.f;
        for (int ki = 0; ki < 3; ++ki) {
            bool okki = pi ? (u ? (ki == 2) : (ki <= 1)) : (u ? (ki >= 1) : (ki == 0));
            if (!okki) continue;
            for (int kj = 0; kj < 3; ++kj) {
                bool okkj = pj ? (v ? (kj == 2) : (kj <= 1)) : (v ? (kj >= 1) : (kj == 0));
                if (okkj) s += w1[((oc * 64 + ic) * 3 + ki) * 3 + kj];
            }
        }
        sW[(pp * 64 + ic) * 4 + u * 2 + v] = s;
    }
    __syncthreads();

    float bias = b1[oc];
    float aA00 = bias, aA01 = bias, aA10 = bias, aA11 = bias;
    float aB00 = bias, aB01 = bias, aB10 = bias, aB11 = bias;

    float mA = (r0 > 0) ? 1.f : 0.f;
    float mB = (r1 < 63) ? 1.f : 0.f;
    float mc0 = (c > 0) ? 1.f : 0.f, mc2 = (c < 63) ? 1.f : 0.f;
    int roA0 = (r0 > 0) ? -64 : 0;
    int roB2 = (r1 < 63) ? 64 : 0;
    int co0 = (c > 0) ? -1 : 0, co2 = (c < 63) ? 1 : 0;

    const float* fbA = feat + bb * 64 * 4096 + r0 * 64 + c;
    const float* fbB = feat + bb * 64 * 4096 + r1 * 64 + c;
    for (int ic = 0; ic < 64; ++ic) {
        const float* pA1 = fbA + ic * 4096;
        const float* pA0 = pA1 + roA0;
        const float* pA2 = pA1 + 64;
        const float* pB1 = fbB + ic * 4096;
        const float* pB0 = pB1 - 64;
        const float* pB2 = pB1 + roB2;

        float vA00 = pA0[co0] * (mA * mc0), vA01 = pA0[0] * mA, vA02 = pA0[co2] * (mA * mc2);
        float vA10 = pA1[co0] * mc0,        vA11 = pA1[0],      vA12 = pA1[co2] * mc2;
        float vA20 = pA2[co0] * mc0,        vA21 = pA2[0],      vA22 = pA2[co2] * mc2;
        float vB00 = pB0[co0] * mc0,        vB01 = pB0[0],      vB02 = pB0[co2] * mc2;
        float vB10 = pB1[co0] * mc0,        vB11 = pB1[0],      vB12 = pB1[co2] * mc2;
        float vB20 = pB2[co0] * (mB * mc0), vB21 = pB2[0] * mB, vB22 = pB2[co2] * (mB * mc2);

        f32x4 w0 = *(const f32x4*)(sW + (0 * 64 + ic) * 4);
        f32x4 w1v = *(const f32x4*)(sW + (1 * 64 + ic) * 4);
        f32x4 w2v = *(const f32x4*)(sW + (2 * 64 + ic) * 4);
        f32x4 w3 = *(const f32x4*)(sW + (3 * 64 + ic) * 4);

        aA00 = fmaf(w0[0], vA00, aA00); aA00 = fmaf(w0[1], vA01, aA00);
        aA00 = fmaf(w0[2], vA10, aA00); aA00 = fmaf(w0[3], vA11, aA00);
        aA01 = fmaf(w1v[0], vA01, aA01); aA01 = fmaf(w1v[1], vA02, aA01);
        aA01 = fmaf(w1v[2], vA11, aA01); aA01 = fmaf(w1v[3], vA12, aA01);
        aA10 = fmaf(w2v[0], vA10, aA10); aA10 = fmaf(w2v[1], vA11, aA10);
        aA10 = fmaf(w2v[2], vA20, aA10); aA10 = fmaf(w2v[3], vA21, aA10);
        aA11 = fmaf(w3[0], vA11, aA11); aA11 = fmaf(w3[1], vA12, aA11);
        aA11 = fmaf(w3[2], vA21, aA11); aA11 = fmaf(w3[3], vA22, aA11);

        aB00 = fmaf(w0[0], vB00, aB00); aB00 = fmaf(w0[1], vB01, aB00);
        aB00 = fmaf(w0[2], vB10, aB00); aB00 = fmaf(w0[3], vB11, aB00);
        aB01 = fmaf(w1v[0], vB01, aB01); aB01 = fmaf(w1v[1], vB02, aB01);
        aB01 = fmaf(w1v[2], vB11, aB01); aB01 = fmaf(w1v[3], vB12, aB01);
        aB10 = fmaf(w2v[0], vB10, aB10); aB10 = fmaf(w2v[1], vB11, aB10);
        aB10 = fmaf(w2v[2], vB20, aB10); aB10 = fmaf(w2v[3], vB21, aB10);
        aB11 = fmaf(w3[0], vB11, aB11); aB11 = fmaf(w3[1], vB12, aB11);
        aB11 = fmaf(w3[2], vB21, aB11); aB11 = fmaf(w3[3], vB22, aB11);
    }

    float* foA = f1 + (bb * 16 + oc) * HWp + (2 * r0) * 128 + 2 * c;
    *reinterpret_cast<float2*>(foA)       = make_float2(fmaxf(aA00, 0.f), fmaxf(aA01, 0.f));
    *reinterpret_cast<float2*>(foA + 128) = make_float2(fmaxf(aA10, 0.f), fmaxf(aA11, 0.f));
    float* foB = f1 + (bb * 16 + oc) * HWp + (2 * r1) * 128 + 2 * c;
    *reinterpret_cast<float2*>(foB)       = make_float2(fmaxf(aB00, 0.f), fmaxf(aB01, 0.f));
    *reinterpret_cast<float2*>(foB + 128) = make_float2(fmaxf(aB10, 0.f), fmaxf(aB11, 0.f));
}

// ---------- K2: conv2 -> fm rows; 8 oc per thread, uniform w2 reads ----------
__global__ __launch_bounds__(THREADS) void k2_conv2_fm(const float* __restrict__ f1,
                                                       const float* __restrict__ w2,
                                                       const float* __restrict__ b2,
                                                       const float* __restrict__ pos,
                                                       float* __restrict__ fm) {
    int tid = threadIdx.x;
    int t = blockIdx.x * THREADS + tid;
    int J = t & 127, I = (t >> 7) & 127, h = (t >> 14) & 1, bb = t >> 15;

    float acc[8];
    #pragma unroll
    for (int o = 0; o < 8; ++o) acc[o] = b2[h * 8 + o];

    int ro0 = (I > 0) ? -128 : 0, ro2 = (I < 127) ? 128 : 0;
    int co0 = (J > 0) ? -1 : 0, co2 = (J < 127) ? 1 : 0;
    float mr0 = (I > 0) ? 1.f : 0.f, mr2 = (I < 127) ? 1.f : 0.f;
    float mcl = (J > 0) ? 1.f : 0.f, mcr = (J < 127) ? 1.f : 0.f;

    const float* fb = f1 + bb * 16 * HWp + I * 128 + J;
    #pragma unroll 4
    for (int ic = 0; ic < 16; ++ic) {
        const float* p1 = fb + ic * HWp;
        const float* p0 = p1 + ro0;
        const float* p2 = p1 + ro2;
        float v0 = p0[co0] * (mr0 * mcl), v1 = p0[0] * mr0, v2 = p0[co2] * (mr0 * mcr);
        float v3 = p1[co0] * mcl,         v4 = p1[0],       v5 = p1[co2] * mcr;
        float v6 = p2[co0] * (mr2 * mcl), v7 = p2[0] * mr2, v8 = p2[co2] * (mr2 * mcr);
        const float* wp = w2 + (h * 8 * 16 + ic) * 9;   // uniform (scalarizable)
        #pragma unroll
        for (int o = 0; o < 8; ++o) {
            const float* w = wp + o * 144;              // (oc*16+ic)*9
            acc[o] = fmaf(v0, w[0], acc[o]); acc[o] = fmaf(v1, w[1], acc[o]);
            acc[o] = fmaf(v2, w[2], acc[o]); acc[o] = fmaf(v3, w[3], acc[o]);
            acc[o] = fmaf(v4, w[4], acc[o]); acc[o] = fmaf(v5, w[5], acc[o]);
            acc[o] = fmaf(v6, w[6], acc[o]); acc[o] = fmaf(v7, w[7], acc[o]);
            acc[o] = fmaf(v8, w[8], acc[o]);
        }
    }
    int n = bb * HWp + I * 128 + J;
    #pragma unroll
    for (int o = 0; o < 8; ++o) fm[n * FMC + h * 8 + o] = acc[o];
    if (h == 0) fm[n * FMC + 16] = pos[(I * 128 + J) * 3];
}

// ---------- K35: GEMM1 via MFMA -> packed bf16 hdn, stashed in d_out --------
// Stash: first 32KB of block b's own even-J weights-row run (k4 reads it in
// its prologue, strictly before overwriting with real weights).
__global__ __launch_bounds__(THREADS) void k35_hdn(const float* __restrict__ fm,
                                                   const short* __restrict__ wB1,
                                                   const float* __restrict__ b1g,
                                                   float* __restrict__ dout) {
    int tid = threadIdx.x;
    int n0 = blockIdx.x * 64;
    int bb = n0 >> 14, tt = n0 & 16383, I = tt >> 7, J0 = tt & 127;
    int s0 = (I & 1) * 2, i0 = I >> 1, jmin = J0 >> 1;
    short* sp = (short*)(dout + (size_t)W_OFF +
                         ((size_t)(bb * 4 + s0) * 4096 + i0 * 64 + jmin) * Mm);

    int w = tid >> 6, l = tid & 63, lm = l & 15, lg = l >> 4;
    int row = w * 16 + lm;                     // local pixel row 0..63
    const float* fr = fm + (n0 + row) * FMC;
    bf16x8 af;
    #pragma unroll
    for (int i = 0; i < 8; ++i) {
        int k = lg * 8 + i;
        float x = (k < FMC) ? fr[k] : 0.f;
        af[i] = f2bf(x);
    }
    const short* wb = wB1 + l * 8;
    int pbase = ((lg >> 1) * 64 + row) * 8 + (lg & 1) * 4;
    #pragma unroll 4
    for (int h = 0; h < 16; ++h) {
        bf16x8 bfr = *(const bf16x8*)(wb + h * 512);
        f32x4 bias = *(const f32x4*)(b1g + h * 16 + lg * 4);
        f32x4 acc = __builtin_amdgcn_mfma_f32_16x16x32_bf16(bfr, af, bias, 0, 0, 0);
        unsigned c0 = (unsigned short)f2bf(fmaxf(acc[0], 0.f));
        unsigned c1 = (unsigned short)f2bf(fmaxf(acc[1], 0.f));
        unsigned c2 = (unsigned short)f2bf(fmaxf(acc[2], 0.f));
        unsigned c3 = (unsigned short)f2bf(fmaxf(acc[3], 0.f));
        uint2 uv; uv.x = c0 | (c1 << 16); uv.y = c2 | (c3 << 16);
        *(uint2*)(sp + pbase + h * 1024) = uv;
    }
}

// ---------------- K4: bf16-MFMA GEMM2 + fused einsum out --------------------
// Operand-swapped MFMA: D[row=m][col=pixel]; dwordx4 weight stores.
// hdn loaded pre-packed from stash; einsum uses transposed x0 slab:
// value(m,pix) = sXT[(jloc+kj)*195 + k3] with k=m/3, kj=k%3, k3=k/3.
__global__ __launch_bounds__(THREADS, 2) void k4_gemm(const short* __restrict__ wB2,
                                                      const float* __restrict__ b2g,
                                                      const float* __restrict__ x0g,
                                                      float* __restrict__ dout) {
    // sA layout (shorts): element (row,k) at ((k>>3)*64 + row)*8 + (k&7)
    __shared__ short sA[16384];     // 32 KB
    __shared__ int   sOB[64];
    __shared__ float sXT[6632];     // [jc 0..33][q 0..191], stride 195
    __shared__ float sOut[4 * 64 * 3];

    int tid = threadIdx.x;
    int n0 = blockIdx.x * 64;
    int bb = n0 >> 14, tt = n0 & 16383, I = tt >> 7, J0 = tt & 127;
    int s0 = (I & 1) * 2, i0 = I >> 1, jmin = J0 >> 1;

    // stage packed hdn (written by k35) into sA: contiguous 32 KB copy
    {
        const short* spc = (const short*)(dout + (size_t)W_OFF +
                             ((size_t)(bb * 4 + s0) * 4096 + i0 * 64 + jmin) * Mm);
        #pragma unroll
        for (int q = 0; q < 8; ++q) {
            int si = (q * 256 + tid) * 8;
            *(bf16x8*)(sA + si) = *(const bf16x8*)(spc + si);
        }
    }
    if (tid < 64) {
        int J = J0 + tid;
        int s = ((I & 1) << 1) | (J & 1);
        int p = ((I >> 1) << 6) | (J >> 1);
        sOB[tid] = W_OFF + ((bb * 4 + s) * 4096 + p) * Mm;
    }
    // x0 slab, transposed: sXT[jc*195 + ch*3+ki]
    {
        const float* x0b = x0g + bb * 64 * 4096;
        for (int e = tid; e < 6528; e += THREADS) {
            int ch = e / 102, r2 = e - ch * 102;
            int ki = r2 / 34, jc = r2 - ki * 34;
            int y = i0 + ki - 1, x = jmin + jc - 1;
            float v = 0.f;
            if ((unsigned)y < 64u && (unsigned)x < 64u) v = x0b[(ch * 64 + y) * 64 + x];
            sXT[jc * 195 + ch * 3 + ki] = v;
        }
    }
    __syncthreads();

    int wid = tid >> 6, l = tid & 63;
    int lm = l & 15, lg = l >> 4;
    int lg3 = lg % 3, lg4 = lg * 4;

    int pixbase[4], jl195[4];
    #pragma unroll
    for (int rt = 0; rt < 4; ++rt) {
        pixbase[rt] = sOB[rt * 16 + lm];
        jl195[rt] = (rt * 8 + (lm >> 1)) * 195;
    }

    const short* aptr = sA + lg * 512 + lm * 8;

    float racc[4][3];
    #pragma unroll
    for (int rt = 0; rt < 4; ++rt) {
        racc[rt][0] = 0.f; racc[rt][1] = 0.f; racc[rt][2] = 0.f;
    }

    for (int mc = wid; mc < 27; mc += 4) {
        int m0 = mc * 64;
        f32x4 acc[4][4];
        #pragma unroll
        for (int ct = 0; ct < 4; ++ct) {
            f32x4 bias4 = *(const f32x4*)(b2g + m0 + ct * 16 + lg * 4);
            #pragma unroll
            for (int rt = 0; rt < 4; ++rt)
                acc[rt][ct] = bias4;
        }
        const short* bbase = wB2 + (size_t)mc * 16384 + l * 8;
        #pragma unroll 2
        for (int s = 0; s < 8; ++s) {
            bf16x8 af[4], bfr[4];
            #pragma unroll
            for (int rt = 0; rt < 4; ++rt)
                af[rt] = *(const bf16x8*)(aptr + s * 2048 + rt * 128);
            #pragma unroll
            for (int ct = 0; ct < 4; ++ct)
                bfr[ct] = *(const bf16x8*)(bbase + (s * 4 + ct) * 512);
            #pragma unroll
            for (int rt = 0; rt < 4; ++rt)
                #pragma unroll
                for (int ct = 0; ct < 4; ++ct)
                    acc[rt][ct] = __builtin_amdgcn_mfma_f32_16x16x32_bf16(
                        bfr[ct], af[rt], acc[rt][ct], 0, 0, 0);
        }
        // store weights: one dwordx4 per (rt,ct)
        #pragma unroll
        for (int rt = 0; rt < 4; ++rt)
            #pragma unroll
            for (int ct = 0; ct < 4; ++ct)
                *(f32x4*)(dout + pixbase[rt] + m0 + ct * 16 + lg * 4) = acc[rt][ct];
        // fused einsum (rotated-o: o = (mc+ct+lg+r)%3); X via div-3 algebra:
        // m=t+r, k=m/3 in {K0,K0+1}: r=0->K0, r=3->K0+1, r=1,2 select on rem3.
#define ACCUM(QB)                                                              \
        _Pragma("unroll")                                                      \
        for (int ct = 0; ct < 4; ++ct) {                                       \
            int t = m0 + ct * 16 + lg4;                                        \
            int K0 = (t * 21846) >> 16;                                        \
            int rem3 = t - 3 * K0;                                             \
            int Q2 = (K0 * 21846) >> 16;                                       \
            int kja = K0 - 3 * Q2;                                             \
            int kqa = kja * 195 + Q2;                                          \
            int kqb = (kja == 2) ? (Q2 + 1) : (kqa + 195);                     \
            _Pragma("unroll")                                                  \
            for (int rt = 0; rt < 4; ++rt) {                                   \
                float xa = sXT[jl195[rt] + kqa];                               \
                float xb = sXT[jl195[rt] + kqb];                               \
                float x1 = (rem3 == 2) ? xb : xa;                              \
                float x2 = (rem3 >= 1) ? xb : xa;                              \
                racc[rt][(QB + ct) % 3] =                                      \
                    fmaf(acc[rt][ct][0], xa, racc[rt][(QB + ct) % 3]);         \
                racc[rt][(QB + ct + 1) % 3] =                                  \
                    fmaf(acc[rt][ct][1], x1, racc[rt][(QB + ct + 1) % 3]);     \
                racc[rt][(QB + ct + 2) % 3] =                                  \
                    fmaf(acc[rt][ct][2], x2, racc[rt][(QB + ct + 2) % 3]);     \
                racc[rt][(QB + ct) % 3] =                                      \
                    fmaf(acc[rt][ct][3], xb, racc[rt][(QB + ct) % 3]);         \
            }                                                                  \
        }
        switch (mc % 3) {
            case 0: ACCUM(0); break;
            case 1: ACCUM(1); break;
            default: ACCUM(2); break;
        }
#undef ACCUM
    }

    // un-rotate (o = (q+lg3)%3), reduce across the 4 lg groups, stash
    #pragma unroll
    for (int rt = 0; rt < 4; ++rt) {
        float q0 = racc[rt][0], q1 = racc[rt][1], q2 = racc[rt][2];
        float a0 = (lg3 == 0) ? q0 : ((lg3 == 1) ? q2 : q1);
        float a1 = (lg3 == 0) ? q1 : ((lg3 == 1) ? q0 : q2);
        float a2 = (lg3 == 0) ? q2 : ((lg3 == 1) ? q1 : q0);
        a0 += __shfl_xor(a0, 16, 64); a0 += __shfl_xor(a0, 32, 64);
        a1 += __shfl_xor(a1, 16, 64); a1 += __shfl_xor(a1, 32, 64);
        a2 += __shfl_xor(a2, 16, 64); a2 += __shfl_xor(a2, 32, 64);
        if (l < 16) {
            float* so = sOut + (wid * 64 + rt * 16 + lm) * 3;
            so[0] = a0; so[1] = a1; so[2] = a2;
        }
    }
    __syncthreads();
    if (tid < 192) {
        float s = sOut[tid] + sOut[192 + tid] + sOut[384 + tid] + sOut[576 + tid];
        int pix = tid / 3, o = tid - 3 * pix;
        dout[bb * 3 * HWp + o * HWp + I * 128 + J0 + pix] = s;
    }
}

extern "C" void kernel_launch(void* const* d_in, const int* in_sizes, int n_in,
                              void* d_out, int out_size, void* d_ws, size_t ws_size,
                              hipStream_t stream) {
    const float* x0      = (const float*)d_in[0];
    const float* feature = (const float*)d_in[1];
    const float* pos     = (const float*)d_in[2];
    const float* w1      = (const float*)d_in[4];
    const float* b1      = (const float*)d_in[5];
    const float* w2      = (const float*)d_in[6];
    const float* b2      = (const float*)d_in[7];
    const float* f2w1_w  = (const float*)d_in[8];
    const float* f2w1_b  = (const float*)d_in[9];
    const float* f2w2_w  = (const float*)d_in[10];
    const float* f2w2_b  = (const float*)d_in[11];

    float* out = (float*)d_out;
    float* ws  = (float*)d_ws;
    float* f1  = ws + F1_OFF;
    float* fm  = ws + FM_OFF;
    short* wB2 = (short*)(ws + WB2_OFF);
    short* wB1 = (short*)(ws + WB1_OFF);

    k13_conv1_cvt<<<1985, THREADS, 0, stream>>>(feature, w1, b1, f1, f2w2_w, wB2,
                                                f2w1_w, wB1);
    k2_conv2_fm<<<(Bsz * 2 * HWp) / THREADS, THREADS, 0, stream>>>(f1, w2, b2, pos, fm);
    k35_hdn<<<Ntot / 64, THREADS, 0, stream>>>(fm, wB1, f2w1_b, out);
    k4_gemm<<<Ntot / 64, THREADS, 0, stream>>>(wB2, f2w2_b, x0, out);
}

// Round 10
// 112.475 us; speedup vs baseline: 1.1248x; 1.1248x over previous
//
#include <hip/hip_runtime.h>

#define THREADS 256

// problem sizes
#define Bsz 2
#define HWp 16384          // 128*128
#define Ntot (Bsz*HWp)     // 32768
#define HID 256
#define Mm 1728
#define FMC 17
#define W_OFF 98304        // 'out' elements precede 'weights' in d_out

// ws layout (in floats)
#define F1_OFF  0
#define F1_SZ   (Bsz*16*HWp)                 // 524288
#define FM_OFF  F1_SZ                        // (unused now)
#define WB2_OFF (FM_OFF + Ntot*FMC)          // bf16 B2 frags: 442368 shorts
#define WB1_OFF (WB2_OFF + (Mm*HID)/2)       // bf16 w1 frags: 8192 shorts

typedef __attribute__((ext_vector_type(8))) short bf16x8;
typedef __attribute__((ext_vector_type(4))) float f32x4;

static __device__ __forceinline__ short f2bf(float x) {
    unsigned u = __builtin_bit_cast(unsigned, x);
    unsigned r = (u + 0x7fff + ((u >> 16) & 1)) >> 16;
    return (short)r;
}

// ---- K13: conv1 512 blocks (1 px/thread) + wB2 cvt 432 blocks + wB1 1 block
__global__ __launch_bounds__(THREADS) void k13_conv1_cvt(const float* __restrict__ feat,
                                                         const float* __restrict__ w1,
                                                         const float* __restrict__ b1,
                                                         float* __restrict__ f1,
                                                         const float* __restrict__ w2g,
                                                         short* __restrict__ wB2,
                                                         const float* __restrict__ w1g,
                                                         short* __restrict__ wB1) {
    int tid = threadIdx.x;
    if (blockIdx.x >= 944) {
        // pack w1 (256x17 f32) -> MFMA B-frags bf16, K padded to 32
        for (int idx = tid; idx < 8192; idx += THREADS) {
            int i = idx & 7, l = (idx >> 3) & 63, h = idx >> 9;
            int k = (l >> 4) * 8 + i, hid = h * 16 + (l & 15);
            wB1[idx] = (k < FMC) ? f2bf(w1g[hid * FMC + k]) : (short)0;
        }
        return;
    }
    if (blockIdx.x >= 512) {
        // f2w2_w (1728x256 fp32) -> bf16 fragment-major; 4 elems/thread
        int t4 = ((blockIdx.x - 512) * THREADS + tid) * 4;
        int i = t4 & 7, l = (t4 >> 3) & 63, ct = (t4 >> 9) & 3, s = (t4 >> 11) & 7, mc = t4 >> 14;
        int col = mc * 64 + ct * 16 + (l & 15);
        int k0 = s * 32 + (l >> 4) * 8 + i;
        f32x4 w = *(const f32x4*)(w2g + col * HID + k0);
        short4 o;
        o.x = f2bf(w[0]); o.y = f2bf(w[1]); o.z = f2bf(w[2]); o.w = f2bf(w[3]);
        *(short4*)(wB2 + t4) = o;
        return;
    }
    // conv1: block = (bb, oc, 4 src rows); thread = one source pixel
    __shared__ float sW[4 * 64 * 4];   // [pp][ic][u*2+v] for this block's oc
    int b = blockIdx.x;
    int rg = b & 15, oc = (b >> 4) & 15, bb = b >> 8;
    int c = tid & 63, r = rg * 4 + (tid >> 6);

    #pragma unroll
    for (int q = 0; q < 4; ++q) {
        int e = tid * 4 + q;
        int v = e & 1, u = (e >> 1) & 1, ic = (e >> 2) & 63, pp = (e >> 8) & 3;
        int pi = pp >> 1, pj = pp & 1;
        float s = 0.f;
        for (int ki = 0; ki < 3; ++ki) {
            bool okki = pi ? (u ? (ki == 2) : (ki <= 1)) : (u ? (ki >= 1) : (ki == 0));
            if (!okki) continue;
            for (int kj = 0; kj < 3; ++kj) {
                bool okkj = pj ? (v ? (kj == 2) : (kj <= 1)) : (v ? (kj >= 1) : (kj == 0));
                if (okkj) s += w1[((oc * 64 + ic) * 3 + ki) * 3 + kj];
            }
        }
        sW[(pp * 64 + ic) * 4 + u * 2 + v] = s;
    }
    __syncthreads();

    float bias = b1[oc];
    float a00 = bias, a01 = bias, a10 = bias, a11 = bias;

    float mt = (r > 0) ? 1.f : 0.f, mb2 = (r < 63) ? 1.f : 0.f;
    float ml = (c > 0) ? 1.f : 0.f, mr2 = (c < 63) ? 1.f : 0.f;
    int ro0 = (r > 0) ? -64 : 0, ro2 = (r < 63) ? 64 : 0;
    int co0 = (c > 0) ? -1 : 0, co2 = (c < 63) ? 1 : 0;

    const float* fb = feat + bb * 64 * 4096 + r * 64 + c;
    for (int ic = 0; ic < 64; ++ic) {
        const float* p1 = fb + ic * 4096;
        const float* p0 = p1 + ro0;
        const float* p2 = p1 + ro2;
        float v00 = p0[co0] * (mt * ml), v01 = p0[0] * mt, v02 = p0[co2] * (mt * mr2);
        float v10 = p1[co0] * ml,        v11 = p1[0],      v12 = p1[co2] * mr2;
        float v20 = p2[co0] * (mb2 * ml), v21 = p2[0] * mb2, v22 = p2[co2] * (mb2 * mr2);

        f32x4 w0 = *(const f32x4*)(sW + (0 * 64 + ic) * 4);
        f32x4 w1v = *(const f32x4*)(sW + (1 * 64 + ic) * 4);
        f32x4 w2v = *(const f32x4*)(sW + (2 * 64 + ic) * 4);
        f32x4 w3 = *(const f32x4*)(sW + (3 * 64 + ic) * 4);

        a00 = fmaf(w0[0], v00, a00); a00 = fmaf(w0[1], v01, a00);
        a00 = fmaf(w0[2], v10, a00); a00 = fmaf(w0[3], v11, a00);
        a01 = fmaf(w1v[0], v01, a01); a01 = fmaf(w1v[1], v02, a01);
        a01 = fmaf(w1v[2], v11, a01); a01 = fmaf(w1v[3], v12, a01);
        a10 = fmaf(w2v[0], v10, a10); a10 = fmaf(w2v[1], v11, a10);
        a10 = fmaf(w2v[2], v20, a10); a10 = fmaf(w2v[3], v21, a10);
        a11 = fmaf(w3[0], v11, a11); a11 = fmaf(w3[1], v12, a11);
        a11 = fmaf(w3[2], v21, a11); a11 = fmaf(w3[3], v22, a11);
    }

    float* fo = f1 + (bb * 16 + oc) * HWp + (2 * r) * 128 + 2 * c;
    *reinterpret_cast<float2*>(fo)       = make_float2(fmaxf(a00, 0.f), fmaxf(a01, 0.f));
    *reinterpret_cast<float2*>(fo + 128) = make_float2(fmaxf(a10, 0.f), fmaxf(a11, 0.f));
}

// ---- K35: conv2 (LDS-staged) + pos -> GEMM1 via MFMA -> packed hdn stash ----
// Stash: first 32KB of block b's own even-J weights-row run of d_out (k4 reads
// it in its prologue before overwriting with real weights).
__global__ __launch_bounds__(THREADS) void k35_hdn(const float* __restrict__ f1,
                                                   const float* __restrict__ w2,
                                                   const float* __restrict__ b2,
                                                   const float* __restrict__ pos,
                                                   const short* __restrict__ wB1,
                                                   const float* __restrict__ b1g,
                                                   float* __restrict__ dout) {
    __shared__ float sF[16 * 3 * 68];   // [ic][di][jc]: f1 neighborhood
    __shared__ float sFM[64 * 33];      // [pix][k0..32], stride 33
    int tid = threadIdx.x;
    int n0 = blockIdx.x * 64;
    int bb = n0 >> 14, tt = n0 & 16383, I = tt >> 7, J0 = tt & 127;

    // stage f1 3-row neighborhood (zero-padded)
    for (int e = tid; e < 16 * 3 * 68; e += THREADS) {
        int jc = e % 68, r2 = e / 68;
        int di = r2 % 3, ic = r2 / 3;
        int y = I + di - 1, x = J0 + jc - 1;
        float v = 0.f;
        if ((unsigned)y < 128u && (unsigned)x < 128u && jc < 66)
            v = f1[(bb * 16 + ic) * HWp + y * 128 + x];
        sF[(ic * 3 + di) * 68 + jc] = v;
    }
    for (int e = tid; e < 64 * 33; e += THREADS) sFM[e] = 0.f;
    __syncthreads();

    // conv2: thread (pix, q) computes oc = q*4..q*4+3 for pixel J0+pix
    {
        int pix = tid & 63, q = tid >> 6;
        float acc[4];
        #pragma unroll
        for (int o = 0; o < 4; ++o) acc[o] = b2[q * 4 + o];
        #pragma unroll 4
        for (int ic = 0; ic < 16; ++ic) {
            float v[9];
            #pragma unroll
            for (int di = 0; di < 3; ++di) {
                const float* row = sF + (ic * 3 + di) * 68 + pix;
                v[di * 3 + 0] = row[0]; v[di * 3 + 1] = row[1]; v[di * 3 + 2] = row[2];
            }
            #pragma unroll
            for (int o = 0; o < 4; ++o) {
                const float* w = w2 + ((q * 4 + o) * 16 + ic) * 9;  // wave-uniform
                acc[o] = fmaf(v[0], w[0], acc[o]); acc[o] = fmaf(v[1], w[1], acc[o]);
                acc[o] = fmaf(v[2], w[2], acc[o]); acc[o] = fmaf(v[3], w[3], acc[o]);
                acc[o] = fmaf(v[4], w[4], acc[o]); acc[o] = fmaf(v[5], w[5], acc[o]);
                acc[o] = fmaf(v[6], w[6], acc[o]); acc[o] = fmaf(v[7], w[7], acc[o]);
                acc[o] = fmaf(v[8], w[8], acc[o]);
            }
        }
        #pragma unroll
        for (int o = 0; o < 4; ++o) sFM[pix * 33 + q * 4 + o] = acc[o];
        if (q == 0) sFM[pix * 33 + 16] = pos[(I * 128 + J0 + pix) * 3];
    }
    __syncthreads();

    // GEMM1 via MFMA, output packed bf16 into stash
    int w = tid >> 6, l = tid & 63, lm = l & 15, lg = l >> 4;
    int row = w * 16 + lm;
    bf16x8 af;
    #pragma unroll
    for (int i = 0; i < 8; ++i) af[i] = f2bf(sFM[row * 33 + lg * 8 + i]);

    int s0 = (I & 1) * 2, i0 = I >> 1, jmin = J0 >> 1;
    short* sp = (short*)(dout + (size_t)W_OFF +
                         ((size_t)(bb * 4 + s0) * 4096 + i0 * 64 + jmin) * Mm);
    const short* wb = wB1 + l * 8;
    int pbase = ((lg >> 1) * 64 + row) * 8 + (lg & 1) * 4;
    #pragma unroll 4
    for (int h = 0; h < 16; ++h) {
        bf16x8 bfr = *(const bf16x8*)(wb + h * 512);
        f32x4 bias = *(const f32x4*)(b1g + h * 16 + lg * 4);
        f32x4 acc = __builtin_amdgcn_mfma_f32_16x16x32_bf16(bfr, af, bias, 0, 0, 0);
        unsigned c0 = (unsigned short)f2bf(fmaxf(acc[0], 0.f));
        unsigned c1 = (unsigned short)f2bf(fmaxf(acc[1], 0.f));
        unsigned c2 = (unsigned short)f2bf(fmaxf(acc[2], 0.f));
        unsigned c3 = (unsigned short)f2bf(fmaxf(acc[3], 0.f));
        uint2 uv; uv.x = c0 | (c1 << 16); uv.y = c2 | (c3 << 16);
        *(uint2*)(sp + pbase + h * 1024) = uv;
    }
}

// ---------------- K4: bf16-MFMA GEMM2 + fused einsum out --------------------
// (unchanged from R9)
__global__ __launch_bounds__(THREADS, 2) void k4_gemm(const short* __restrict__ wB2,
                                                      const float* __restrict__ b2g,
                                                      const float* __restrict__ x0g,
                                                      float* __restrict__ dout) {
    __shared__ short sA[16384];     // 32 KB
    __shared__ int   sOB[64];
    __shared__ float sXT[6632];     // [jc 0..33][q 0..191], stride 195
    __shared__ float sOut[4 * 64 * 3];

    int tid = threadIdx.x;
    int n0 = blockIdx.x * 64;
    int bb = n0 >> 14, tt = n0 & 16383, I = tt >> 7, J0 = tt & 127;
    int s0 = (I & 1) * 2, i0 = I >> 1, jmin = J0 >> 1;

    {
        const short* spc = (const short*)(dout + (size_t)W_OFF +
                             ((size_t)(bb * 4 + s0) * 4096 + i0 * 64 + jmin) * Mm);
        #pragma unroll
        for (int q = 0; q < 8; ++q) {
            int si = (q * 256 + tid) * 8;
            *(bf16x8*)(sA + si) = *(const bf16x8*)(spc + si);
        }
    }
    if (tid < 64) {
        int J = J0 + tid;
        int s = ((I & 1) << 1) | (J & 1);
        int p = ((I >> 1) << 6) | (J >> 1);
        sOB[tid] = W_OFF + ((bb * 4 + s) * 4096 + p) * Mm;
    }
    {
        const float* x0b = x0g + bb * 64 * 4096;
        for (int e = tid; e < 6528; e += THREADS) {
            int ch = e / 102, r2 = e - ch * 102;
            int ki = r2 / 34, jc = r2 - ki * 34;
            int y = i0 + ki - 1, x = jmin + jc - 1;
            float v = 0.f;
            if ((unsigned)y < 64u && (unsigned)x < 64u) v = x0b[(ch * 64 + y) * 64 + x];
            sXT[jc * 195 + ch * 3 + ki] = v;
        }
    }
    __syncthreads();

    int wid = tid >> 6, l = tid & 63;
    int lm = l & 15, lg = l >> 4;
    int lg3 = lg % 3, lg4 = lg * 4;

    int pixbase[4], jl195[4];
    #pragma unroll
    for (int rt = 0; rt < 4; ++rt) {
        pixbase[rt] = sOB[rt * 16 + lm];
        jl195[rt] = (rt * 8 + (lm >> 1)) * 195;
    }

    const short* aptr = sA + lg * 512 + lm * 8;

    float racc[4][3];
    #pragma unroll
    for (int rt = 0; rt < 4; ++rt) {
        racc[rt][0] = 0.f; racc[rt][1] = 0.f; racc[rt][2] = 0.f;
    }

    for (int mc = wid; mc < 27; mc += 4) {
        int m0 = mc * 64;
        f32x4 acc[4][4];
        #pragma unroll
        for (int ct = 0; ct < 4; ++ct) {
            f32x4 bias4 = *(const f32x4*)(b2g + m0 + ct * 16 + lg * 4);
            #pragma unroll
            for (int rt = 0; rt < 4; ++rt)
                acc[rt][ct] = bias4;
        }
        const short* bbase = wB2 + (size_t)mc * 16384 + l * 8;
        #pragma unroll 2
        for (int s = 0; s < 8; ++s) {
            bf16x8 af[4], bfr[4];
            #pragma unroll
            for (int rt = 0; rt < 4; ++rt)
                af[rt] = *(const bf16x8*)(aptr + s * 2048 + rt * 128);
            #pragma unroll
            for (int ct = 0; ct < 4; ++ct)
                bfr[ct] = *(const bf16x8*)(bbase + (s * 4 + ct) * 512);
            #pragma unroll
            for (int rt = 0; rt < 4; ++rt)
                #pragma unroll
                for (int ct = 0; ct < 4; ++ct)
                    acc[rt][ct] = __builtin_amdgcn_mfma_f32_16x16x32_bf16(
                        bfr[ct], af[rt], acc[rt][ct], 0, 0, 0);
        }
        #pragma unroll
        for (int rt = 0; rt < 4; ++rt)
            #pragma unroll
            for (int ct = 0; ct < 4; ++ct)
                *(f32x4*)(dout + pixbase[rt] + m0 + ct * 16 + lg * 4) = acc[rt][ct];
#define ACCUM(QB)                                                              \
        _Pragma("unroll")                                                      \
        for (int ct = 0; ct < 4; ++ct) {                                       \
            int t = m0 + ct * 16 + lg4;                                        \
            int K0 = (t * 21846) >> 16;                                        \
            int rem3 = t - 3 * K0;                                             \
            int Q2 = (K0 * 21846) >> 16;                                       \
            int kja = K0 - 3 * Q2;                                             \
            int kqa = kja * 195 + Q2;                                          \
            int kqb = (kja == 2) ? (Q2 + 1) : (kqa + 195);                     \
            _Pragma("unroll")                                                  \
            for (int rt = 0; rt < 4; ++rt) {                                   \
                float xa = sXT[jl195[rt] + kqa];                               \
                float xb = sXT[jl195[rt] + kqb];                               \
                float x1 = (rem3 == 2) ? xb : xa;                              \
                float x2 = (rem3 >= 1) ? xb : xa;                              \
                racc[rt][(QB + ct) % 3] =                                      \
                    fmaf(acc[rt][ct][0], xa, racc[rt][(QB + ct) % 3]);         \
                racc[rt][(QB + ct + 1) % 3] =                                  \
                    fmaf(acc[rt][ct][1], x1, racc[rt][(QB + ct + 1) % 3]);     \
                racc[rt][(QB + ct + 2) % 3] =                                  \
                    fmaf(acc[rt][ct][2], x2, racc[rt][(QB + ct + 2) % 3]);     \
                racc[rt][(QB + ct) % 3] =                                      \
                    fmaf(acc[rt][ct][3], xb, racc[rt][(QB + ct) % 3]);         \
            }                                                                  \
        }
        switch (mc % 3) {
            case 0: ACCUM(0); break;
            case 1: ACCUM(1); break;
            default: ACCUM(2); break;
        }
#undef ACCUM
    }

    #pragma unroll
    for (int rt = 0; rt < 4; ++rt) {
        float q0 = racc[rt][0], q1 = racc[rt][1], q2 = racc[rt][2];
        float a0 = (lg3 == 0) ? q0 : ((lg3 == 1) ? q2 : q1);
        float a1 = (lg3 == 0) ? q1 : ((lg3 == 1) ? q0 : q2);
        float a2 = (lg3 == 0) ? q2 : ((lg3 == 1) ? q1 : q0);
        a0 += __shfl_xor(a0, 16, 64); a0 += __shfl_xor(a0, 32, 64);
        a1 += __shfl_xor(a1, 16, 64); a1 += __shfl_xor(a1, 32, 64);
        a2 += __shfl_xor(a2, 16, 64); a2 += __shfl_xor(a2, 32, 64);
        if (l < 16) {
            float* so = sOut + (wid * 64 + rt * 16 + lm) * 3;
            so[0] = a0; so[1] = a1; so[2] = a2;
        }
    }
    __syncthreads();
    if (tid < 192) {
        float s = sOut[tid] + sOut[192 + tid] + sOut[384 + tid] + sOut[576 + tid];
        int pix = tid / 3, o = tid - 3 * pix;
        dout[bb * 3 * HWp + o * HWp + I * 128 + J0 + pix] = s;
    }
}

extern "C" void kernel_launch(void* const* d_in, const int* in_sizes, int n_in,
                              void* d_out, int out_size, void* d_ws, size_t ws_size,
                              hipStream_t stream) {
    const float* x0      = (const float*)d_in[0];
    const float* feature = (const float*)d_in[1];
    const float* pos     = (const float*)d_in[2];
    const float* w1      = (const float*)d_in[4];
    const float* b1      = (const float*)d_in[5];
    const float* w2      = (const float*)d_in[6];
    const float* b2      = (const float*)d_in[7];
    const float* f2w1_w  = (const float*)d_in[8];
    const float* f2w1_b  = (const float*)d_in[9];
    const float* f2w2_w  = (const float*)d_in[10];
    const float* f2w2_b  = (const float*)d_in[11];

    float* out = (float*)d_out;
    float* ws  = (float*)d_ws;
    float* f1  = ws + F1_OFF;
    short* wB2 = (short*)(ws + WB2_OFF);
    short* wB1 = (short*)(ws + WB1_OFF);

    // 512 conv1 + 432 cvt + 1 wB1-pack blocks in one dispatch
    k13_conv1_cvt<<<945, THREADS, 0, stream>>>(feature, w1, b1, f1, f2w2_w, wB2,
                                               f2w1_w, wB1);
    k35_hdn<<<Ntot / 64, THREADS, 0, stream>>>(f1, w2, b2, pos, wB1, f2w1_b, out);
    k4_gemm<<<Ntot / 64, THREADS, 0, stream>>>(wB2, f2w2_b, x0, out);
}

// Round 11
// 108.539 us; speedup vs baseline: 1.1656x; 1.0363x over previous
//
#include <hip/hip_runtime.h>

#define THREADS 256

// problem sizes
#define Bsz 2
#define HWp 16384          // 128*128
#define Ntot (Bsz*HWp)     // 32768
#define HID 256
#define Mm 1728
#define FMC 17
#define W_OFF 98304        // 'out' elements precede 'weights' in d_out

// ws layout (in floats)
#define F1_OFF  0
#define F1_SZ   (Bsz*16*HWp)                 // 524288
#define WB2_OFF (F1_SZ + Ntot*FMC)           // bf16 B2 frags: 442368 shorts
#define WB1_OFF (WB2_OFF + (Mm*HID)/2)       // bf16 w1 frags: 8192 shorts

typedef __attribute__((ext_vector_type(8))) short bf16x8;
typedef __attribute__((ext_vector_type(4))) float f32x4;

static __device__ __forceinline__ short f2bf(float x) {
    unsigned u = __builtin_bit_cast(unsigned, x);
    unsigned r = (u + 0x7fff + ((u >> 16) & 1)) >> 16;
    return (short)r;
}
static __device__ __forceinline__ float bf2f(short s) {
    unsigned u = ((unsigned)(unsigned short)s) << 16;
    return __builtin_bit_cast(float, u);
}

// ---- K13: conv1 512 blocks (1 px/thread) + wB2 cvt 432 blocks + wB1 1 block
__global__ __launch_bounds__(THREADS) void k13_conv1_cvt(const float* __restrict__ feat,
                                                         const float* __restrict__ w1,
                                                         const float* __restrict__ b1,
                                                         float* __restrict__ f1,
                                                         const float* __restrict__ w2g,
                                                         short* __restrict__ wB2,
                                                         const float* __restrict__ w1g,
                                                         short* __restrict__ wB1) {
    int tid = threadIdx.x;
    if (blockIdx.x >= 944) {
        for (int idx = tid; idx < 8192; idx += THREADS) {
            int i = idx & 7, l = (idx >> 3) & 63, h = idx >> 9;
            int k = (l >> 4) * 8 + i, hid = h * 16 + (l & 15);
            wB1[idx] = (k < FMC) ? f2bf(w1g[hid * FMC + k]) : (short)0;
        }
        return;
    }
    if (blockIdx.x >= 512) {
        int t4 = ((blockIdx.x - 512) * THREADS + tid) * 4;
        int i = t4 & 7, l = (t4 >> 3) & 63, ct = (t4 >> 9) & 3, s = (t4 >> 11) & 7, mc = t4 >> 14;
        int col = mc * 64 + ct * 16 + (l & 15);
        int k0 = s * 32 + (l >> 4) * 8 + i;
        f32x4 w = *(const f32x4*)(w2g + col * HID + k0);
        short4 o;
        o.x = f2bf(w[0]); o.y = f2bf(w[1]); o.z = f2bf(w[2]); o.w = f2bf(w[3]);
        *(short4*)(wB2 + t4) = o;
        return;
    }
    // conv1: block = (bb, oc, 4 src rows); thread = one source pixel
    __shared__ float sW[4 * 64 * 4];   // [pp][ic][u*2+v] for this block's oc
    int b = blockIdx.x;
    int rg = b & 15, oc = (b >> 4) & 15, bb = b >> 8;
    int c = tid & 63, r = rg * 4 + (tid >> 6);

    #pragma unroll
    for (int q = 0; q < 4; ++q) {
        int e = tid * 4 + q;
        int v = e & 1, u = (e >> 1) & 1, ic = (e >> 2) & 63, pp = (e >> 8) & 3;
        int pi = pp >> 1, pj = pp & 1;
        float s = 0.f;
        for (int ki = 0; ki < 3; ++ki) {
            bool okki = pi ? (u ? (ki == 2) : (ki <= 1)) : (u ? (ki >= 1) : (ki == 0));
            if (!okki) continue;
            for (int kj = 0; kj < 3; ++kj) {
                bool okkj = pj ? (v ? (kj == 2) : (kj <= 1)) : (v ? (kj >= 1) : (kj == 0));
                if (okkj) s += w1[((oc * 64 + ic) * 3 + ki) * 3 + kj];
            }
        }
        sW[(pp * 64 + ic) * 4 + u * 2 + v] = s;
    }
    __syncthreads();

    float bias = b1[oc];
    float a00 = bias, a01 = bias, a10 = bias, a11 = bias;

    float mt = (r > 0) ? 1.f : 0.f, mb2 = (r < 63) ? 1.f : 0.f;
    float ml = (c > 0) ? 1.f : 0.f, mr2 = (c < 63) ? 1.f : 0.f;
    int ro0 = (r > 0) ? -64 : 0, ro2 = (r < 63) ? 64 : 0;
    int co0 = (c > 0) ? -1 : 0, co2 = (c < 63) ? 1 : 0;

    const float* fb = feat + bb * 64 * 4096 + r * 64 + c;
    for (int ic = 0; ic < 64; ++ic) {
        const float* p1 = fb + ic * 4096;
        const float* p0 = p1 + ro0;
        const float* p2 = p1 + ro2;
        float v00 = p0[co0] * (mt * ml), v01 = p0[0] * mt, v02 = p0[co2] * (mt * mr2);
        float v10 = p1[co0] * ml,        v11 = p1[0],      v12 = p1[co2] * mr2;
        float v20 = p2[co0] * (mb2 * ml), v21 = p2[0] * mb2, v22 = p2[co2] * (mb2 * mr2);

        f32x4 w0 = *(const f32x4*)(sW + (0 * 64 + ic) * 4);
        f32x4 w1v = *(const f32x4*)(sW + (1 * 64 + ic) * 4);
        f32x4 w2v = *(const f32x4*)(sW + (2 * 64 + ic) * 4);
        f32x4 w3 = *(const f32x4*)(sW + (3 * 64 + ic) * 4);

        a00 = fmaf(w0[0], v00, a00); a00 = fmaf(w0[1], v01, a00);
        a00 = fmaf(w0[2], v10, a00); a00 = fmaf(w0[3], v11, a00);
        a01 = fmaf(w1v[0], v01, a01); a01 = fmaf(w1v[1], v02, a01);
        a01 = fmaf(w1v[2], v11, a01); a01 = fmaf(w1v[3], v12, a01);
        a10 = fmaf(w2v[0], v10, a10); a10 = fmaf(w2v[1], v11, a10);
        a10 = fmaf(w2v[2], v20, a10); a10 = fmaf(w2v[3], v21, a10);
        a11 = fmaf(w3[0], v11, a11); a11 = fmaf(w3[1], v12, a11);
        a11 = fmaf(w3[2], v21, a11); a11 = fmaf(w3[3], v22, a11);
    }

    float* fo = f1 + (bb * 16 + oc) * HWp + (2 * r) * 128 + 2 * c;
    *reinterpret_cast<float2*>(fo)       = make_float2(fmaxf(a00, 0.f), fmaxf(a01, 0.f));
    *reinterpret_cast<float2*>(fo + 128) = make_float2(fmaxf(a10, 0.f), fmaxf(a11, 0.f));
}

// ---- K4: conv2 + GEMM1(MFMA) + GEMM2(MFMA) + fused einsum, one kernel -----
// LDS: sA 32KB persists; uni phase1 = {sF bf16 [ic*3+di][66], sFM f32 [64][33]},
// phase2 = {sXT bf16 [jc][195-stride], sOut}. ~49.4 KB -> 3 blocks/CU.
__global__ __launch_bounds__(THREADS, 3) void k4_fused(const float* __restrict__ f1,
                                                       const float* __restrict__ w2,
                                                       const float* __restrict__ b2,
                                                       const float* __restrict__ pos,
                                                       const short* __restrict__ wB1,
                                                       const float* __restrict__ b1g,
                                                       const short* __restrict__ wB2,
                                                       const float* __restrict__ b2g,
                                                       const float* __restrict__ x0g,
                                                       float* __restrict__ dout) {
    __shared__ short sA[16384];     // 32 KB packed bf16 hdn
    __shared__ int   sOB[64];
    __shared__ float uni[4084];     // 16.3 KB phase-union

    short* sF  = (short*)uni;       // phase1: 3168 shorts  [ic*3+di][jc<66]
    float* sFM = uni + 1584;        // phase1: 2112 floats  [pix][33]
    short* sXT = (short*)uni;       // phase2: 6632 shorts  [jc][q], stride 195
    float* sOut = uni + 3316;       // phase2: 768 floats

    int tid = threadIdx.x;
    int n0 = blockIdx.x * 64;
    int bb = n0 >> 14, tt = n0 & 16383, I = tt >> 7, J0 = tt & 127;
    int i0 = I >> 1, jmin = J0 >> 1;

    // ---- phase 1a: stage f1 neighborhood (bf16) + zero sFM tail ----
    for (int e = tid; e < 3168; e += THREADS) {
        int jc = e % 66, r2 = e / 66;
        int di = r2 % 3, ic = r2 / 3;
        int y = I + di - 1, x = J0 + jc - 1;
        float v = 0.f;
        if ((unsigned)y < 128u && (unsigned)x < 128u)
            v = f1[(bb * 16 + ic) * HWp + y * 128 + x];
        sF[(ic * 3 + di) * 66 + jc] = f2bf(v);
    }
    for (int e = tid; e < 2112; e += THREADS) sFM[e] = 0.f;
    if (tid < 64) {
        int J = J0 + tid;
        int s = ((I & 1) << 1) | (J & 1);
        int p = ((I >> 1) << 6) | (J >> 1);
        sOB[tid] = W_OFF + ((bb * 4 + s) * 4096 + p) * Mm;
    }
    __syncthreads();

    // ---- phase 1b: conv2 -> sFM (thread = (pix, 4 oc)) ----
    {
        int pix = tid & 63, q = tid >> 6;
        float acc[4];
        #pragma unroll
        for (int o = 0; o < 4; ++o) acc[o] = b2[q * 4 + o];
        #pragma unroll 4
        for (int ic = 0; ic < 16; ++ic) {
            float v[9];
            #pragma unroll
            for (int di = 0; di < 3; ++di) {
                const short* row = sF + (ic * 3 + di) * 66 + pix;
                v[di * 3 + 0] = bf2f(row[0]);
                v[di * 3 + 1] = bf2f(row[1]);
                v[di * 3 + 2] = bf2f(row[2]);
            }
            #pragma unroll
            for (int o = 0; o < 4; ++o) {
                const float* w = w2 + ((q * 4 + o) * 16 + ic) * 9;  // wave-uniform
                acc[o] = fmaf(v[0], w[0], acc[o]); acc[o] = fmaf(v[1], w[1], acc[o]);
                acc[o] = fmaf(v[2], w[2], acc[o]); acc[o] = fmaf(v[3], w[3], acc[o]);
                acc[o] = fmaf(v[4], w[4], acc[o]); acc[o] = fmaf(v[5], w[5], acc[o]);
                acc[o] = fmaf(v[6], w[6], acc[o]); acc[o] = fmaf(v[7], w[7], acc[o]);
                acc[o] = fmaf(v[8], w[8], acc[o]);
            }
        }
        #pragma unroll
        for (int o = 0; o < 4; ++o) sFM[pix * 33 + q * 4 + o] = acc[o];
        if (q == 0) sFM[pix * 33 + 16] = pos[(I * 128 + J0 + pix) * 3];
    }
    __syncthreads();

    int wv = tid >> 6, l = tid & 63, lm = l & 15, lg = l >> 4;

    // ---- phase 1c: read fm row fragment for GEMM1 ----
    int row = wv * 16 + lm;
    bf16x8 af1;
    #pragma unroll
    for (int i = 0; i < 8; ++i) af1[i] = f2bf(sFM[row * 33 + lg * 8 + i]);
    __syncthreads();   // all sFM/sF reads done; uni is now free

    // ---- phase 1d: GEMM1 MFMA -> sA (packed), and stage sXT ----
    {
        const short* wb = wB1 + l * 8;
        int pbase = ((lg >> 1) * 64 + row) * 8 + (lg & 1) * 4;
        #pragma unroll 4
        for (int h = 0; h < 16; ++h) {
            bf16x8 bfr = *(const bf16x8*)(wb + h * 512);
            f32x4 bias = *(const f32x4*)(b1g + h * 16 + lg * 4);
            f32x4 acc = __builtin_amdgcn_mfma_f32_16x16x32_bf16(bfr, af1, bias, 0, 0, 0);
            unsigned c0 = (unsigned short)f2bf(fmaxf(acc[0], 0.f));
            unsigned c1 = (unsigned short)f2bf(fmaxf(acc[1], 0.f));
            unsigned c2 = (unsigned short)f2bf(fmaxf(acc[2], 0.f));
            unsigned c3 = (unsigned short)f2bf(fmaxf(acc[3], 0.f));
            uint2 uv; uv.x = c0 | (c1 << 16); uv.y = c2 | (c3 << 16);
            *(uint2*)(sA + pbase + h * 1024) = uv;
        }
    }
    {
        const float* x0b = x0g + bb * 64 * 4096;
        for (int e = tid; e < 6528; e += THREADS) {
            int ch = e / 102, r2 = e - ch * 102;
            int ki = r2 / 34, jc = r2 - ki * 34;
            int y = i0 + ki - 1, x = jmin + jc - 1;
            float v = 0.f;
            if ((unsigned)y < 64u && (unsigned)x < 64u) v = x0b[(ch * 64 + y) * 64 + x];
            sXT[jc * 195 + ch * 3 + ki] = f2bf(v);
        }
    }
    __syncthreads();

    // ---- phase 2: GEMM2 + weights store + fused einsum ----
    int lg3 = lg % 3, lg4 = lg * 4;
    int pixbase[4], jl195[4];
    #pragma unroll
    for (int rt = 0; rt < 4; ++rt) {
        pixbase[rt] = sOB[rt * 16 + lm];
        jl195[rt] = (rt * 8 + (lm >> 1)) * 195;
    }

    const short* aptr = sA + lg * 512 + lm * 8;

    float racc[4][3];
    #pragma unroll
    for (int rt = 0; rt < 4; ++rt) {
        racc[rt][0] = 0.f; racc[rt][1] = 0.f; racc[rt][2] = 0.f;
    }

    for (int mc = wv; mc < 27; mc += 4) {
        int m0 = mc * 64;
        f32x4 acc[4][4];
        #pragma unroll
        for (int ct = 0; ct < 4; ++ct) {
            f32x4 bias4 = *(const f32x4*)(b2g + m0 + ct * 16 + lg * 4);
            #pragma unroll
            for (int rt = 0; rt < 4; ++rt)
                acc[rt][ct] = bias4;
        }
        const short* bbase = wB2 + (size_t)mc * 16384 + l * 8;
        #pragma unroll 2
        for (int s = 0; s < 8; ++s) {
            bf16x8 af[4], bfr[4];
            #pragma unroll
            for (int rt = 0; rt < 4; ++rt)
                af[rt] = *(const bf16x8*)(aptr + s * 2048 + rt * 128);
            #pragma unroll
            for (int ct = 0; ct < 4; ++ct)
                bfr[ct] = *(const bf16x8*)(bbase + (s * 4 + ct) * 512);
            #pragma unroll
            for (int rt = 0; rt < 4; ++rt)
                #pragma unroll
                for (int ct = 0; ct < 4; ++ct)
                    acc[rt][ct] = __builtin_amdgcn_mfma_f32_16x16x32_bf16(
                        bfr[ct], af[rt], acc[rt][ct], 0, 0, 0);
        }
        #pragma unroll
        for (int rt = 0; rt < 4; ++rt)
            #pragma unroll
            for (int ct = 0; ct < 4; ++ct)
                *(f32x4*)(dout + pixbase[rt] + m0 + ct * 16 + lg * 4) = acc[rt][ct];
#define ACCUM(QB)                                                              \
        _Pragma("unroll")                                                      \
        for (int ct = 0; ct < 4; ++ct) {                                       \
            int t = m0 + ct * 16 + lg4;                                        \
            int K0 = (t * 21846) >> 16;                                        \
            int rem3 = t - 3 * K0;                                             \
            int Q2 = (K0 * 21846) >> 16;                                       \
            int kja = K0 - 3 * Q2;                                             \
            int kqa = kja * 195 + Q2;                                          \
            int kqb = (kja == 2) ? (Q2 + 1) : (kqa + 195);                     \
            _Pragma("unroll")                                                  \
            for (int rt = 0; rt < 4; ++rt) {                                   \
                float xa = bf2f(sXT[jl195[rt] + kqa]);                         \
                float xb = bf2f(sXT[jl195[rt] + kqb]);                         \
                float x1 = (rem3 == 2) ? xb : xa;                              \
                float x2 = (rem3 >= 1) ? xb : xa;                              \
                racc[rt][(QB + ct) % 3] =                                      \
                    fmaf(acc[rt][ct][0], xa, racc[rt][(QB + ct) % 3]);         \
                racc[rt][(QB + ct + 1) % 3] =                                  \
                    fmaf(acc[rt][ct][1], x1, racc[rt][(QB + ct + 1) % 3]);     \
                racc[rt][(QB + ct + 2) % 3] =                                  \
                    fmaf(acc[rt][ct][2], x2, racc[rt][(QB + ct + 2) % 3]);     \
                racc[rt][(QB + ct) % 3] =                                      \
                    fmaf(acc[rt][ct][3], xb, racc[rt][(QB + ct) % 3]);         \
            }                                                                  \
        }
        switch (mc % 3) {
            case 0: ACCUM(0); break;
            case 1: ACCUM(1); break;
            default: ACCUM(2); break;
        }
#undef ACCUM
    }

    // un-rotate (o = (q+lg3)%3), reduce across the 4 lg groups, stash
    #pragma unroll
    for (int rt = 0; rt < 4; ++rt) {
        float q0 = racc[rt][0], q1 = racc[rt][1], q2 = racc[rt][2];
        float a0 = (lg3 == 0) ? q0 : ((lg3 == 1) ? q2 : q1);
        float a1 = (lg3 == 0) ? q1 : ((lg3 == 1) ? q0 : q2);
        float a2 = (lg3 == 0) ? q2 : ((lg3 == 1) ? q1 : q0);
        a0 += __shfl_xor(a0, 16, 64); a0 += __shfl_xor(a0, 32, 64);
        a1 += __shfl_xor(a1, 16, 64); a1 += __shfl_xor(a1, 32, 64);
        a2 += __shfl_xor(a2, 16, 64); a2 += __shfl_xor(a2, 32, 64);
        if (l < 16) {
            float* so = sOut + (wv * 64 + rt * 16 + lm) * 3;
            so[0] = a0; so[1] = a1; so[2] = a2;
        }
    }
    __syncthreads();
    if (tid < 192) {
        float s = sOut[tid] + sOut[192 + tid] + sOut[384 + tid] + sOut[576 + tid];
        int pix = tid / 3, o = tid - 3 * pix;
        dout[bb * 3 * HWp + o * HWp + I * 128 + J0 + pix] = s;
    }
}

extern "C" void kernel_launch(void* const* d_in, const int* in_sizes, int n_in,
                              void* d_out, int out_size, void* d_ws, size_t ws_size,
                              hipStream_t stream) {
    const float* x0      = (const float*)d_in[0];
    const float* feature = (const float*)d_in[1];
    const float* pos     = (const float*)d_in[2];
    const float* w1      = (const float*)d_in[4];
    const float* b1      = (const float*)d_in[5];
    const float* w2      = (const float*)d_in[6];
    const float* b2      = (const float*)d_in[7];
    const float* f2w1_w  = (const float*)d_in[8];
    const float* f2w1_b  = (const float*)d_in[9];
    const float* f2w2_w  = (const float*)d_in[10];
    const float* f2w2_b  = (const float*)d_in[11];

    float* out = (float*)d_out;
    float* ws  = (float*)d_ws;
    float* f1  = ws + F1_OFF;
    short* wB2 = (short*)(ws + WB2_OFF);
    short* wB1 = (short*)(ws + WB1_OFF);

    k13_conv1_cvt<<<945, THREADS, 0, stream>>>(feature, w1, b1, f1, f2w2_w, wB2,
                                               f2w1_w, wB1);
    k4_fused<<<Ntot / 64, THREADS, 0, stream>>>(f1, w2, b2, pos, wB1, f2w1_b,
                                                wB2, f2w2_b, x0, out);
}